// Round 1
// 392.856 us; speedup vs baseline: 1.0734x; 1.0734x over previous
//
#include <hip/hip_runtime.h>

// ---- problem constants ----
static constexpr int SEQ = 20, FEAT = 5, NU1 = 10, NU2 = 7, NU3 = 4, NOUT = 4;

// MFMA fragment types
typedef short bf16x8 __attribute__((ext_vector_type(8)));
typedef float f32x4  __attribute__((ext_vector_type(4)));

// ---- K-slot scheme (unchanged numerics) ----
// Each logical input i occupies 4 K-slots: A=(Whi,Whi,Wlo,Wlo), B=(vhi,vlo,vhi,vlo)
// -> contribution (Whi+Wlo)(vhi+vlo): full fp32-class precision.
// Bias rides as the LAST input index of each layer with B = P(1.0) = (1,0,1,0).
//
// Input orderings (recurrent h FIRST so B-fragments map to per-lane p-registers):
//  L1: [h1_0..9 (i=0..9),  x_0..4 (i=10..14), b1 (i=15)]  -> 2 K-tiles, 3 M-tiles
//  L2: [h1_0..9 (i=0..9),  h2_0..6 (i=10..16), b2 (i=17)] -> 3 K-tiles, 2 M-tiles
//  L3: [h2_0..6 (i=0..6),  h3_0..3 (i=7..10),  b3 (i=11)] -> 2 K-tiles, 1 M-tile
//  D : [h3_0..3 (i=0..3),  bd (i=4)]                      -> 1 K-tile,  1 M-tile
// A-frag ids: id = base + tau*KT + kap; bases {0,6,12}, D=14. 15 frags total.
//
// B-frag per lane (n = lane&15, q = lane>>4), K-tile kap: needs packed pairs
// P(i0), P(i1) for i0 = 8*kap + 2q, i1 = i0+1, laid out {v0,v0,v1,v1}.
// All P values live in lane registers of the same wave -> ds_bpermute, no LDS.

__device__ __forceinline__ unsigned short bf16_hi_rne(float x) {
    unsigned u = __float_as_uint(x);
    return (unsigned short)((u + 0x7FFF + ((u >> 16) & 1)) >> 16);
}
__device__ __forceinline__ unsigned short bf16_trunc(float x) {
    return (unsigned short)(__float_as_uint(x) >> 16);
}
__device__ __forceinline__ float bf16_to_f(unsigned short h) {
    return __uint_as_float(((unsigned)h) << 16);
}
// pack value as (hi | lo<<16): bf16 pair, hi in low half
__device__ __forceinline__ unsigned hpack(float h) {
    unsigned u = __float_as_uint(h);
    unsigned r = (u + 0x7FFF + ((u >> 16) & 1)) >> 16;
    unsigned lo = __float_as_uint(h - __uint_as_float(r << 16)) >> 16;
    return r | (lo << 16);
}

__device__ __forceinline__ float sigm(float x) {
    return __builtin_amdgcn_rcpf(1.0f + __builtin_amdgcn_exp2f(x * -1.4426950408889634f));
}
__device__ __forceinline__ float ftanh(float x) {
    return 1.0f - 2.0f * __builtin_amdgcn_rcpf(1.0f + __builtin_amdgcn_exp2f(x * 2.8853900817779268f));
}

// z = (i,f,g,o) for one unit (lane-local); updates c, returns packed h (hi,lo)
__device__ __forceinline__ unsigned act_unit(const f32x4 z, float& c) {
    float gi = sigm(z[0]), gf = sigm(z[1]), gg = ftanh(z[2]), go = sigm(z[3]);
    c = gf * c + gi * gg;
    return hpack(go * ftanh(c));
}

__device__ __forceinline__ unsigned bperm(int idx, unsigned v) {
    return (unsigned)__builtin_amdgcn_ds_bpermute(idx, (int)v);
}
__device__ __forceinline__ bf16x8 bfrag(unsigned v0, unsigned v1) {
    uint4 u{v0, v0, v1, v1};
    return __builtin_bit_cast(bf16x8, u);
}

// ---------- pre-kernel: build A-fragments into ws (15 frags x 64 lanes x 16B) ----------
__global__ void build_afrags(const float* Wk1, const float* Wr1, const float* b1,
                             const float* Wk2, const float* Wr2, const float* b2,
                             const float* Wk3, const float* Wr3, const float* b3,
                             const float* Wd,  const float* bd, unsigned* ws) {
    const int lane = threadIdx.x;  // 64 threads
    const int Us[3] = {NU1, NU2, NU3};
    const int nF[3] = {10, 10, 7};   // rows in FIRST block (recurrent for L1, feed-in h1 for L2, h2 for L3)
    const int nS[3] = {5, 7, 4};     // rows in SECOND block
    const float* Fm[3] = {Wr1, Wk2, Wk3};
    const float* Sm[3] = {Wk1, Wr2, Wr3};
    const float* Bs[3] = {b1, b2, b3};
    const int baseid[3] = {0, 6, 12}, KT[3] = {2, 3, 2}, MT[3] = {3, 2, 1};
    for (int L = 0; L < 3; ++L) {
        const int U = Us[L], nf = nF[L], ns = nS[L];
        const int Itot = nf + ns;          // bias lives at i == Itot
        for (int tau = 0; tau < MT[L]; ++tau)
        for (int kap = 0; kap < KT[L]; ++kap) {
            const int id = baseid[L] + tau * KT[L] + kap;
            unsigned short h8[8];
            for (int j = 0; j < 8; ++j) {
                const int m = lane & 15;
                const int k = kap * 32 + (lane >> 4) * 8 + j;
                const int i = k >> 2, cls = k & 3;
                const int u = tau * 4 + (m >> 2), g = m & 3, col = g * U + u;
                unsigned short v = 0;
                if (u < U && i <= Itot) {
                    float W = (i < nf)   ? Fm[L][i * 4 * U + col]
                            : (i < Itot) ? Sm[L][(i - nf) * 4 * U + col]
                                         : Bs[L][col];
                    unsigned short hi = bf16_hi_rne(W);
                    v = (cls < 2) ? hi : bf16_trunc(W - bf16_to_f(hi));
                }
                h8[j] = v;
            }
            for (int d = 0; d < 4; ++d)
                ws[id * 256 + lane * 4 + d] = (unsigned)h8[2 * d] | ((unsigned)h8[2 * d + 1] << 16);
        }
    }
    {   // dense: id 14, rows m=0..3 are outputs; inputs h3 (i=0..3), bias i=4
        unsigned short h8[8];
        for (int j = 0; j < 8; ++j) {
            const int m = lane & 15;
            const int k = (lane >> 4) * 8 + j;
            const int i = k >> 2, cls = k & 3;
            unsigned short v = 0;
            if (m < NOUT && i <= 4) {
                float W = (i < 4) ? Wd[i * NOUT + m] : bd[m];
                unsigned short hi = bf16_hi_rne(W);
                v = (cls < 2) ? hi : bf16_trunc(W - bf16_to_f(hi));
            }
            h8[j] = v;
        }
        for (int d = 0; d < 4; ++d)
            ws[14 * 256 + lane * 4 + d] = (unsigned)h8[2 * d] | ((unsigned)h8[2 * d + 1] << 16);
    }
}

// ---------- main kernel: 16 batch elems per wave, zero LDS, bpermute B-frags ----------
__global__ __launch_bounds__(256, 4) void lstm3_mfma(
    const float* __restrict__ x, const unsigned* __restrict__ wsA,
    float* __restrict__ out, int B) {
    const int tid = threadIdx.x;
    const int lane = tid & 63;
    const int n = lane & 15;        // batch elem within group (= B/C col)
    const int q = lane >> 4;        // K-quad (B operand) / row-quad (C)

    // A-fragments: 15 x 16B per lane, coalesced (compiler places these in AGPRs)
    bf16x8 af[15];
#pragma unroll
    for (int i = 0; i < 15; ++i) {
        uint4 v = ((const uint4*)wsA)[i * 64 + lane];
        af[i] = __builtin_bit_cast(bf16x8, v);
    }

    // bpermute byte indices (loop-invariant per lane)
    const int ie  = (n + 16 * ((2 * q) & 3))     << 2;  // q -> src-q 0,2,0,2
    const int io  = (n + 16 * ((2 * q + 1) & 3)) << 2;  // q -> 1,3,1,3
    const int ie2 = (n + 16 * ((2 * q + 2) & 3)) << 2;  // q>=1 -> 0,2,0
    const int io2 = (n + 16 * ((2 * q + 3) & 3)) << 2;  // q>=1 -> 1,3,1
    const int in0 = n << 2, in1 = (n + 16) << 2, in2 = (n + 32) << 2;

    const f32x4 zro = {0.f, 0.f, 0.f, 0.f};

    const int ngrp = B >> 4;
    const int gw = (blockIdx.x * blockDim.x + tid) >> 6;
    const int nw = (gridDim.x * blockDim.x) >> 6;

    for (int grp = gw; grp < ngrp; grp += nw) {
        const float* xr = x + (size_t)grp * 16 * (SEQ * FEAT) + n * (SEQ * FEAT);
        float* ob = out + (size_t)grp * 16 * (SEQ * NOUT) + n * (SEQ * NOUT);

        // packed-h state (P(0)=0 == h0=0), carried B-frag pieces, cell states
        unsigned p1a = 0, p1b = 0, p1c = 0, p2a = 0, p2b = 0, p3 = 0;
        unsigned F0v0 = 0, F0v1 = 0, tC0 = 0, tC1 = 0;
        float c10 = 0.f, c11 = 0.f, c12 = 0.f, c20 = 0.f, c21 = 0.f, c30 = 0.f;

        // preload x for t=0: q=1:(x0,x1) q=2:(x2,x3) q=3:(x4,-)
        float xa = 0.f, xc = 0.f;
        if (q != 0) {
            const float* p = xr + 2 * (q - 1);
            xa = p[0];
            if (q != 3) xc = p[1];
        }

#pragma unroll 1
        for (int t = 0; t < SEQ; ++t) {
            unsigned xP0 = hpack(xa), xP1 = hpack(xc);
            // software prefetch next timestep's x
            {
                const int tn = (t + 1 < SEQ) ? t + 1 : 0;
                if (q != 0) {
                    const float* p = xr + tn * FEAT + 2 * (q - 1);
                    xa = p[0];
                    if (q != 3) xc = p[1];
                }
            }
            // F1 (L1 kap1): q=0:(h1_8,h1_9) q=1:(x0,x1) q=2:(x2,x3) q=3:(x4,bias)
            unsigned F1v0 = (q == 0) ? tC0 : xP0;
            unsigned F1v1 = (q == 0) ? tC1 : ((q == 3) ? 0x3F80u : xP1);

            // ---- L1: uses F0/tC = h1^{t-1}, x_t ----
            f32x4 z0 = __builtin_amdgcn_mfma_f32_16x16x32_bf16(af[0], bfrag(F0v0, F0v1), zro, 0, 0, 0);
            z0 = __builtin_amdgcn_mfma_f32_16x16x32_bf16(af[1], bfrag(F1v0, F1v1), z0, 0, 0, 0);
            f32x4 z1 = __builtin_amdgcn_mfma_f32_16x16x32_bf16(af[2], bfrag(F0v0, F0v1), zro, 0, 0, 0);
            z1 = __builtin_amdgcn_mfma_f32_16x16x32_bf16(af[3], bfrag(F1v0, F1v1), z1, 0, 0, 0);
            f32x4 z2 = __builtin_amdgcn_mfma_f32_16x16x32_bf16(af[4], bfrag(F0v0, F0v1), zro, 0, 0, 0);
            z2 = __builtin_amdgcn_mfma_f32_16x16x32_bf16(af[5], bfrag(F1v0, F1v1), z2, 0, 0, 0);
            p1a = act_unit(z0, c10);                 // P(h1_q)
            p1b = act_unit(z1, c11);                 // P(h1_{4+q})
            p1c = act_unit(z2, c12);                 // P(h1_{8+q}), valid q<2

            // ---- rebuild F0/tC from h1^t (serves L2 now, L1 next step) ----
            {
                unsigned ae = bperm(ie, p1a), be = bperm(ie, p1b);
                unsigned ao = bperm(io, p1a), bo = bperm(io, p1b);
                F0v0 = (q < 2) ? ae : be;            // h1_{2q}
                F0v1 = (q < 2) ? ao : bo;            // h1_{2q+1}
                tC0 = bperm(in0, p1c);               // h1_8
                tC1 = bperm(in1, p1c);               // h1_9
            }
            // ---- L2 frags: h1^t (tC) + h2^{t-1} (old p2) ----
            unsigned F2v0, F2v1, F3v0;
            {
                unsigned de = bperm(ie2, p2a), ee = bperm(ie2, p2b);
                unsigned dd = bperm(io2, p2a), eo = bperm(io2, p2b);
                F2v0 = (q == 0) ? tC0 : ((q < 3) ? de : ee);  // h1_8 | h2_{2q-2}
                F2v1 = (q == 0) ? tC1 : ((q < 3) ? dd : eo);  // h1_9 | h2_{2q-1}
                F3v0 = bperm(in2, p2b);                       // h2_6 (q=0 slot)
            }
            const unsigned F3v1 = 0x3F80u;                    // bias P(1.0)

            // ---- L2 ----
            f32x4 y0 = __builtin_amdgcn_mfma_f32_16x16x32_bf16(af[6], bfrag(F0v0, F0v1), zro, 0, 0, 0);
            y0 = __builtin_amdgcn_mfma_f32_16x16x32_bf16(af[7], bfrag(F2v0, F2v1), y0, 0, 0, 0);
            y0 = __builtin_amdgcn_mfma_f32_16x16x32_bf16(af[8], bfrag(F3v0, F3v1), y0, 0, 0, 0);
            f32x4 y1 = __builtin_amdgcn_mfma_f32_16x16x32_bf16(af[9], bfrag(F0v0, F0v1), zro, 0, 0, 0);
            y1 = __builtin_amdgcn_mfma_f32_16x16x32_bf16(af[10], bfrag(F2v0, F2v1), y1, 0, 0, 0);
            y1 = __builtin_amdgcn_mfma_f32_16x16x32_bf16(af[11], bfrag(F3v0, F3v1), y1, 0, 0, 0);
            p2a = act_unit(y0, c20);                 // P(h2_q)
            p2b = act_unit(y1, c21);                 // P(h2_{4+q}), valid q<3

            // ---- L3 frags: h2^t (new p2) + h3^{t-1} (old p3) ----
            unsigned F4v0, F4v1, F5v0, F5v1;
            {
                unsigned ge = bperm(ie, p2a), he = bperm(ie, p2b);
                unsigned go = bperm(io, p2a), ho = bperm(io, p2b);
                unsigned pp0 = bperm(in0, p3);
                F4v0 = (q < 2) ? ge : he;                        // h2_{2q}
                F4v1 = (q < 2) ? go : ((q == 2) ? ho : pp0);     // h2_{2q+1} | h3_0
                F5v0 = bperm(io, p3);                            // q=0: h3_1, q=1: h3_3
                F5v1 = (q == 1) ? 0x3F80u : bperm(in2, p3);      // q=0: h3_2, q=1: bias
            }
            // ---- L3 ----
            f32x4 w0 = __builtin_amdgcn_mfma_f32_16x16x32_bf16(af[12], bfrag(F4v0, F4v1), zro, 0, 0, 0);
            w0 = __builtin_amdgcn_mfma_f32_16x16x32_bf16(af[13], bfrag(F5v0, F5v1), w0, 0, 0, 0);
            p3 = act_unit(w0, c30);                  // P(h3_q)

            // ---- D frag: h3^t ----
            unsigned F6v0, F6v1;
            {
                unsigned ue = bperm(ie, p3), uo = bperm(io, p3);
                F6v0 = (q == 2) ? 0x3F80u : ue;      // q=0: h3_0, q=1: h3_2, q=2: bias
                F6v1 = uo;                           // q=0: h3_1, q=1: h3_3
            }
            f32x4 o0 = __builtin_amdgcn_mfma_f32_16x16x32_bf16(af[14], bfrag(F6v0, F6v1), zro, 0, 0, 0);
            if (q == 0) {
                float4 o4;
                o4.x = sigm(o0[0]); o4.y = sigm(o0[1]);
                o4.z = sigm(o0[2]); o4.w = sigm(o0[3]);
                *(float4*)(ob + t * NOUT) = o4;
            }
        }
    }
}

extern "C" void kernel_launch(void* const* d_in, const int* in_sizes, int n_in,
                              void* d_out, int out_size, void* d_ws, size_t ws_size,
                              hipStream_t stream) {
    const float* x   = (const float*)d_in[0];
    const float* Wk1 = (const float*)d_in[1];
    const float* Wr1 = (const float*)d_in[2];
    const float* b1  = (const float*)d_in[3];
    const float* Wk2 = (const float*)d_in[4];
    const float* Wr2 = (const float*)d_in[5];
    const float* b2  = (const float*)d_in[6];
    const float* Wk3 = (const float*)d_in[7];
    const float* Wr3 = (const float*)d_in[8];
    const float* b3  = (const float*)d_in[9];
    const float* Wd  = (const float*)d_in[10];
    const float* bd  = (const float*)d_in[11];
    float* out = (float*)d_out;
    unsigned* ws = (unsigned*)d_ws;

    const int B = in_sizes[0] / (SEQ * FEAT);

    build_afrags<<<1, 64, 0, stream>>>(Wk1, Wr1, b1, Wk2, Wr2, b2,
                                       Wk3, Wr3, b3, Wd, bd, ws);
    lstm3_mfma<<<2048, 256, 0, stream>>>(x, ws, out, B);
}

// Round 2
// 386.161 us; speedup vs baseline: 1.0920x; 1.0173x over previous
//
#include <hip/hip_runtime.h>

// ---- problem constants ----
static constexpr int SEQ = 20, FEAT = 5, NU1 = 10, NU2 = 7, NU3 = 4, NOUT = 4;

// MFMA fragment types
typedef short bf16x8 __attribute__((ext_vector_type(8)));
typedef float f32x4  __attribute__((ext_vector_type(4)));

// ---- K-slot scheme (numerics unchanged) ----
// Input i -> 4 K-slots: A=(Whi,Whi,Wlo,Wlo), B=(vhi,vlo,vhi,vlo); sum = (Whi+Wlo)(vhi+vlo).
// Bias: A=(bhi,blo,0,0), B=P(1.0)=0x3F803F80 -> slots (1,1,1,1) -> bhi+blo exact.
//
// Lane (n = lane&15 batch-col, q = lane>>4) supplies B inputs (8*kap+2q, 8*kap+2q+1).
// Act outputs land as: lane q holds h_{q} (pa), h_{4+q} (pb), h_{8+q} (pc).
// INTERLEAVED input orderings make recurrent B-frags lane-local:
//  L1 (16 in): [h1_0,h1_4,h1_1,h1_5,h1_2,h1_6,h1_3,h1_7 | h1_8,h1_9,x0,x1,x2,x3,x4,b1]
//  L2 (18 in): [same h1 pairs | h1_8,h1_9,h2_0,h2_4,h2_1,h2_5 | h2_2,h2_6? no: see map]
//      i10..15 = h2_0,h2_4,h2_1,h2_5,h2_2,h2_6 ; i16 = h2_3 ; i17 = b2
//  L3 (12 in): [h2_0,h2_4,h2_1,h2_5,h2_2,h2_6,h2_3,h3_0 | h3_1,h3_2,h3_3,b3]
//  D  (5 in) : [h3_0,h3_1,h3_2,h3_3,bd]
// Cross-lane needs per timestep (5 bpermutes total):
//  t9  = p1c from q'=1        (h1_9 broadcast)
//  s2a/s2b = p2a/p2b from q-1 (h2 shift; q0 gets h2_3 for K-tile2)
//  rot/rot2 = p3 from q+1/q+2 (h3 distribution; reused by D now and L3 next step)

__device__ __forceinline__ unsigned short bf16_hi_rne(float x) {
    unsigned u = __float_as_uint(x);
    return (unsigned short)((u + 0x7FFF + ((u >> 16) & 1)) >> 16);
}
__device__ __forceinline__ unsigned short bf16_trunc(float x) {
    return (unsigned short)(__float_as_uint(x) >> 16);
}
__device__ __forceinline__ float bf16_to_f(unsigned short h) {
    return __uint_as_float(((unsigned)h) << 16);
}
// pack value as (hi | lo<<16): hi = RNE bf16 via v_cvt_pk, lo = trunc(h - hi)
__device__ __forceinline__ unsigned hpack(float h) {
    unsigned rp;
    asm("v_cvt_pk_bf16_f32 %0, %1, %1" : "=v"(rp) : "v"(h));
    float lo = h - __uint_as_float(rp << 16);
    // result bytes: {lo.b3, lo.b2, rp.b1, rp.b0}
    return __builtin_amdgcn_perm(__float_as_uint(lo), rp, 0x07060100u);
}

__device__ __forceinline__ float sigm(float x) {
    return __builtin_amdgcn_rcpf(1.0f + __builtin_amdgcn_exp2f(x * -1.4426950408889634f));
}
__device__ __forceinline__ float ftanh(float x) {
    return 1.0f - 2.0f * __builtin_amdgcn_rcpf(1.0f + __builtin_amdgcn_exp2f(x * 2.8853900817779268f));
}

// z = (i,f,g,o) for one unit (lane-local); updates c, returns packed h (hi,lo)
__device__ __forceinline__ unsigned act_unit(const f32x4 z, float& c) {
    float gi = sigm(z[0]), gf = sigm(z[1]), gg = ftanh(z[2]), go = sigm(z[3]);
    c = gf * c + gi * gg;
    return hpack(go * ftanh(c));
}

__device__ __forceinline__ unsigned bperm(int idx, unsigned v) {
    return (unsigned)__builtin_amdgcn_ds_bpermute(idx, (int)v);
}
__device__ __forceinline__ bf16x8 bfrag(unsigned v0, unsigned v1) {
    uint4 u{v0, v0, v1, v1};
    return __builtin_bit_cast(bf16x8, u);
}

// ---------- pre-kernel: build A-fragments into ws (15 frags x 64 lanes x 16B) ----------
__global__ void build_afrags(const float* Wk1, const float* Wr1, const float* b1,
                             const float* Wk2, const float* Wr2, const float* b2,
                             const float* Wk3, const float* Wr3, const float* b3,
                             const float* Wd,  const float* bd, unsigned* ws) {
    const int lane = threadIdx.x;  // 64 threads
    const int m = lane & 15;
    const int qh = lane >> 4;

    // ---- L1: ids 0..5 (tau*2+kap), U=10 ----
    for (int tau = 0; tau < 3; ++tau)
    for (int kap = 0; kap < 2; ++kap) {
        unsigned short h8[8];
        for (int j = 0; j < 8; ++j) {
            const int k = kap * 32 + qh * 8 + j;
            const int i = k >> 2, cls = k & 3;
            const int u = tau * 4 + (m >> 2), col = (m & 3) * NU1 + u;
            unsigned short v = 0;
            if (u < NU1) {
                if (i < 15) {
                    float W;
                    if (i < 8)       W = Wr1[((i >> 1) + 4 * (i & 1)) * 40 + col];
                    else if (i < 10) W = Wr1[i * 40 + col];
                    else             W = Wk1[(i - 10) * 40 + col];
                    unsigned short hi = bf16_hi_rne(W);
                    v = (cls < 2) ? hi : bf16_trunc(W - bf16_to_f(hi));
                } else if (i == 15) {
                    float bv = b1[col];
                    unsigned short hi = bf16_hi_rne(bv);
                    v = (cls == 0) ? hi : ((cls == 1) ? bf16_trunc(bv - bf16_to_f(hi)) : (unsigned short)0);
                }
            }
            h8[j] = v;
        }
        const int id = tau * 2 + kap;
        for (int d = 0; d < 4; ++d)
            ws[id * 256 + lane * 4 + d] = (unsigned)h8[2 * d] | ((unsigned)h8[2 * d + 1] << 16);
    }
    // ---- L2: ids 6..11 (6+tau*3+kap), U=7 ----
    for (int tau = 0; tau < 2; ++tau)
    for (int kap = 0; kap < 3; ++kap) {
        unsigned short h8[8];
        for (int j = 0; j < 8; ++j) {
            const int k = kap * 32 + qh * 8 + j;
            const int i = k >> 2, cls = k & 3;
            const int u = tau * 4 + (m >> 2), col = (m & 3) * NU2 + u;
            unsigned short v = 0;
            if (u < NU2) {
                if (i < 17) {
                    float W;
                    if (i < 8)        W = Wk2[((i >> 1) + 4 * (i & 1)) * 28 + col];
                    else if (i < 10)  W = Wk2[i * 28 + col];
                    else if (i < 16)  W = Wr2[(((i - 10) >> 1) + 4 * ((i - 10) & 1)) * 28 + col];
                    else              W = Wr2[3 * 28 + col];
                    unsigned short hi = bf16_hi_rne(W);
                    v = (cls < 2) ? hi : bf16_trunc(W - bf16_to_f(hi));
                } else if (i == 17) {
                    float bv = b2[col];
                    unsigned short hi = bf16_hi_rne(bv);
                    v = (cls == 0) ? hi : ((cls == 1) ? bf16_trunc(bv - bf16_to_f(hi)) : (unsigned short)0);
                }
            }
            h8[j] = v;
        }
        const int id = 6 + tau * 3 + kap;
        for (int d = 0; d < 4; ++d)
            ws[id * 256 + lane * 4 + d] = (unsigned)h8[2 * d] | ((unsigned)h8[2 * d + 1] << 16);
    }
    // ---- L3: ids 12,13, U=4 (single M-tile) ----
    for (int kap = 0; kap < 2; ++kap) {
        unsigned short h8[8];
        for (int j = 0; j < 8; ++j) {
            const int k = kap * 32 + qh * 8 + j;
            const int i = k >> 2, cls = k & 3;
            const int u = m >> 2, col = (m & 3) * NU3 + u;
            unsigned short v = 0;
            if (i < 11) {
                float W;
                if (i < 6)       W = Wk3[((i >> 1) + 4 * (i & 1)) * 16 + col];
                else if (i == 6) W = Wk3[3 * 16 + col];
                else             W = Wr3[(i - 7) * 16 + col];
                unsigned short hi = bf16_hi_rne(W);
                v = (cls < 2) ? hi : bf16_trunc(W - bf16_to_f(hi));
            } else if (i == 11) {
                float bv = b3[col];
                unsigned short hi = bf16_hi_rne(bv);
                v = (cls == 0) ? hi : ((cls == 1) ? bf16_trunc(bv - bf16_to_f(hi)) : (unsigned short)0);
            }
            h8[j] = v;
        }
        const int id = 12 + kap;
        for (int d = 0; d < 4; ++d)
            ws[id * 256 + lane * 4 + d] = (unsigned)h8[2 * d] | ((unsigned)h8[2 * d + 1] << 16);
    }
    // ---- D: id 14, rows m=0..3 ----
    {
        unsigned short h8[8];
        for (int j = 0; j < 8; ++j) {
            const int k = qh * 8 + j;
            const int i = k >> 2, cls = k & 3;
            unsigned short v = 0;
            if (m < NOUT) {
                if (i < 4) {
                    float W = Wd[i * NOUT + m];
                    unsigned short hi = bf16_hi_rne(W);
                    v = (cls < 2) ? hi : bf16_trunc(W - bf16_to_f(hi));
                } else if (i == 4) {
                    float bv = bd[m];
                    unsigned short hi = bf16_hi_rne(bv);
                    v = (cls == 0) ? hi : ((cls == 1) ? bf16_trunc(bv - bf16_to_f(hi)) : (unsigned short)0);
                }
            }
            h8[j] = v;
        }
        for (int d = 0; d < 4; ++d)
            ws[14 * 256 + lane * 4 + d] = (unsigned)h8[2 * d] | ((unsigned)h8[2 * d + 1] << 16);
    }
}

// ---------- main kernel: 16 batch elems per wave, lane-local recurrence ----------
__global__ __launch_bounds__(256, 4) void lstm3_mfma(
    const float* __restrict__ x, const unsigned* __restrict__ wsA,
    float* __restrict__ out, int B) {
    const int tid = threadIdx.x;
    const int lane = tid & 63;
    const int n = lane & 15;        // batch elem within group
    const int q = lane >> 4;        // K-quad / unit-quad

    // A-fragments: 15 x 16B per lane
    bf16x8 af[15];
#pragma unroll
    for (int i = 0; i < 15; ++i) {
        uint4 v = ((const uint4*)wsA)[i * 64 + lane];
        af[i] = __builtin_bit_cast(bf16x8, v);
    }

    // loop-invariant bpermute byte indices
    const int i_h19 = (n + 16) << 2;                    // read q'=1
    const int i_sh  = (n + 16 * ((q + 3) & 3)) << 2;    // read q'=q-1
    const int i_r1  = (n + 16 * ((q + 1) & 3)) << 2;    // read q'=q+1
    const int i_r2  = (n + 16 * ((q + 2) & 3)) << 2;    // read q'=q+2

    const unsigned ONE = 0x3F803F80u;                   // P(1.0) hi+lo
    const f32x4 zro = {0.f, 0.f, 0.f, 0.f};

    const int ngrp = B >> 4;
    const int gw = (blockIdx.x * blockDim.x + tid) >> 6;
    const int nw = (gridDim.x * blockDim.x) >> 6;

    for (int grp = gw; grp < ngrp; grp += nw) {
        const float* xr = x + (size_t)grp * 16 * (SEQ * FEAT) + n * (SEQ * FEAT);
        float* ob = out + (size_t)grp * 16 * (SEQ * NOUT) + n * (SEQ * NOUT);

        unsigned p1a = 0, p1b = 0, p1c = 0, t9 = 0;
        unsigned p2a = 0, p2b = 0, p3 = 0, rot = 0, rot2 = 0;
        float c10 = 0.f, c11 = 0.f, c12 = 0.f, c20 = 0.f, c21 = 0.f, c30 = 0.f;

        // preload x for t=0: q=1:(x0,x1) q=2:(x2,x3) q=3:(x4,-)
        float xa = 0.f, xc = 0.f;
        if (q != 0) {
            const float* p = xr + 2 * (q - 1);
            xa = p[0];
            if (q != 3) xc = p[1];
        }

#pragma unroll 1
        for (int t = 0; t < SEQ; ++t) {
            const unsigned xP0 = hpack(xa), xP1 = hpack(xc);
            // software prefetch next timestep's x
            {
                const int tn = (t + 1 < SEQ) ? t + 1 : 0;
                if (q != 0) {
                    const float* p = xr + tn * FEAT + 2 * (q - 1);
                    xa = p[0];
                    if (q != 3) xc = p[1];
                }
            }
            // ---- L1: B-frags from h1^{t-1} (lane-local) + x_t ----
            bf16x8 bF0 = bfrag(p1a, p1b);                         // (h1_q, h1_{4+q})^{t-1}
            unsigned F1v0 = (q == 0) ? p1c : xP0;                 // h1_8 | x_{2q-2}
            unsigned F1v1 = (q == 0) ? t9 : ((q == 3) ? ONE : xP1);
            bf16x8 bF1 = bfrag(F1v0, F1v1);
            f32x4 z0 = __builtin_amdgcn_mfma_f32_16x16x32_bf16(af[0], bF0, zro, 0, 0, 0);
            z0 = __builtin_amdgcn_mfma_f32_16x16x32_bf16(af[1], bF1, z0, 0, 0, 0);
            f32x4 z1 = __builtin_amdgcn_mfma_f32_16x16x32_bf16(af[2], bF0, zro, 0, 0, 0);
            z1 = __builtin_amdgcn_mfma_f32_16x16x32_bf16(af[3], bF1, z1, 0, 0, 0);
            f32x4 z2 = __builtin_amdgcn_mfma_f32_16x16x32_bf16(af[4], bF0, zro, 0, 0, 0);
            z2 = __builtin_amdgcn_mfma_f32_16x16x32_bf16(af[5], bF1, z2, 0, 0, 0);
            // shift h2^{t-1} while L1 computes (no dependency)
            const unsigned s2a = bperm(i_sh, p2a);
            const unsigned s2b = bperm(i_sh, p2b);
            p1a = act_unit(z0, c10);                              // h1_q^t
            p1b = act_unit(z1, c11);                              // h1_{4+q}^t
            p1c = act_unit(z2, c12);                              // h1_{8+q}^t (q<2)
            t9  = bperm(i_h19, p1c);                              // h1_9^t everywhere
            // ---- L2: h1^t lane-local + h2^{t-1} shifted ----
            bf16x8 bA  = bfrag(p1a, p1b);
            unsigned F2v0 = (q == 0) ? p1c : s2a;                 // h1_8 | h2_{q-1}
            unsigned F2v1 = (q == 0) ? t9  : s2b;                 // h1_9 | h2_{q+3}
            bf16x8 bF2 = bfrag(F2v0, F2v1);
            bf16x8 bF3 = bfrag(s2a, ONE);                         // q0: (h2_3, b2)
            f32x4 y0 = __builtin_amdgcn_mfma_f32_16x16x32_bf16(af[6], bA, zro, 0, 0, 0);
            y0 = __builtin_amdgcn_mfma_f32_16x16x32_bf16(af[7], bF2, y0, 0, 0, 0);
            y0 = __builtin_amdgcn_mfma_f32_16x16x32_bf16(af[8], bF3, y0, 0, 0, 0);
            f32x4 y1 = __builtin_amdgcn_mfma_f32_16x16x32_bf16(af[9], bA, zro, 0, 0, 0);
            y1 = __builtin_amdgcn_mfma_f32_16x16x32_bf16(af[10], bF2, y1, 0, 0, 0);
            y1 = __builtin_amdgcn_mfma_f32_16x16x32_bf16(af[11], bF3, y1, 0, 0, 0);
            p2a = act_unit(y0, c20);                              // h2_q^t
            p2b = act_unit(y1, c21);                              // h2_{4+q}^t (q<3)
            // ---- L3: h2^t lane-local + h3^{t-1} via rot/rot2 (prev iter) ----
            bf16x8 bF4 = bfrag(p2a, (q == 3) ? rot : p2b);        // q3: (h2_3, h3_0)
            unsigned F5v0 = (q == 0) ? rot  : rot2;               // h3_1 | h3_3
            unsigned F5v1 = (q == 0) ? rot2 : ONE;                // h3_2 | b3
            bf16x8 bF5 = bfrag(F5v0, F5v1);
            f32x4 w0 = __builtin_amdgcn_mfma_f32_16x16x32_bf16(af[12], bF4, zro, 0, 0, 0);
            w0 = __builtin_amdgcn_mfma_f32_16x16x32_bf16(af[13], bF5, w0, 0, 0, 0);
            p3 = act_unit(w0, c30);                               // h3_q^t
            rot  = bperm(i_r1, p3);                               // h3_{q+1}^t
            rot2 = bperm(i_r2, p3);                               // h3_{q+2}^t
            // ---- D: h3^t ----
            unsigned F6v0 = (q == 0) ? p3 : ((q == 1) ? rot : ONE);   // h3_0 | h3_2 | bd
            unsigned F6v1 = (q == 0) ? rot : rot2;                    // h3_1 | h3_3
            f32x4 o0 = __builtin_amdgcn_mfma_f32_16x16x32_bf16(af[14], bfrag(F6v0, F6v1), zro, 0, 0, 0);
            if (q == 0) {
                float4 o4;
                o4.x = sigm(o0[0]); o4.y = sigm(o0[1]);
                o4.z = sigm(o0[2]); o4.w = sigm(o0[3]);
                *(float4*)(ob + t * NOUT) = o4;
            }
        }
    }
}

extern "C" void kernel_launch(void* const* d_in, const int* in_sizes, int n_in,
                              void* d_out, int out_size, void* d_ws, size_t ws_size,
                              hipStream_t stream) {
    const float* x   = (const float*)d_in[0];
    const float* Wk1 = (const float*)d_in[1];
    const float* Wr1 = (const float*)d_in[2];
    const float* b1  = (const float*)d_in[3];
    const float* Wk2 = (const float*)d_in[4];
    const float* Wr2 = (const float*)d_in[5];
    const float* b2  = (const float*)d_in[6];
    const float* Wk3 = (const float*)d_in[7];
    const float* Wr3 = (const float*)d_in[8];
    const float* b3  = (const float*)d_in[9];
    const float* Wd  = (const float*)d_in[10];
    const float* bd  = (const float*)d_in[11];
    float* out = (float*)d_out;
    unsigned* ws = (unsigned*)d_ws;

    const int B = in_sizes[0] / (SEQ * FEAT);

    build_afrags<<<1, 64, 0, stream>>>(Wk1, Wr1, b1, Wk2, Wr2, b2,
                                       Wk3, Wr3, b3, Wd, bd, ws);
    lstm3_mfma<<<2048, 256, 0, stream>>>(x, ws, out, B);
}

// Round 3
// 376.038 us; speedup vs baseline: 1.1214x; 1.0269x over previous
//
#include <hip/hip_runtime.h>

// ---- problem constants ----
static constexpr int SEQ = 20, FEAT = 5, NU1 = 10, NU2 = 7, NU3 = 4, NOUT = 4;

// MFMA fragment types
typedef short bf16x8 __attribute__((ext_vector_type(8)));
typedef float f32x4  __attribute__((ext_vector_type(4)));

static constexpr unsigned ONE_P = 0x3F803F80u;   // P(1.0) hi+lo pair

// ---- K-slot scheme (numerics unchanged) ----
// Input i -> 4 K-slots: A=(Whi,Whi,Wlo,Wlo), B=(vhi,vlo,vhi,vlo); sum = (Whi+Wlo)(vhi+vlo).
// Bias: A=(bhi,blo,0,0), B=P(1.0) -> bhi+blo exact.
// Lane (n = lane&15 batch-col, q = lane>>4) supplies B inputs (8*kap+2q, 8*kap+2q+1).
// INTERLEAVED input orderings make recurrent B-frags lane-local (see round-2 notes):
//  L1: [h1_0,h1_4,h1_1,h1_5,h1_2,h1_6,h1_3,h1_7 | h1_8,h1_9,x0..x4,b1]
//  L2: [h1 pairs | h1_8,h1_9,h2_0,h2_4,h2_1,h2_5 | h2_2,h2_6,h2_3,b2 ...]
//  L3: [h2_0,h2_4,h2_1,h2_5,h2_2,h2_6,h2_3,h3_0 | h3_1,h3_2,h3_3,b3]
//  D : [h3_0,h3_1,h3_2,h3_3,bd], A-rows REPLICATED so every lane gets all 4 outputs.
// Cross-lane: 5 bpermutes/timestep (t9, s2a/s2b, rot/rot2).
// Dense sigmoid DEFERRED: lane (n,q) buffers output q each t; every 4 t one
// sigmoid batch + store (uniform branch) -> 4 sigm/t becomes 1 sigm/t.
// TWO groups per wave, phase-interleaved for ILP (trans-pipe saturation).

__device__ __forceinline__ unsigned short bf16_hi_rne(float x) {
    unsigned u = __float_as_uint(x);
    return (unsigned short)((u + 0x7FFF + ((u >> 16) & 1)) >> 16);
}
__device__ __forceinline__ unsigned short bf16_trunc(float x) {
    return (unsigned short)(__float_as_uint(x) >> 16);
}
__device__ __forceinline__ float bf16_to_f(unsigned short h) {
    return __uint_as_float(((unsigned)h) << 16);
}
// pack value as (hi | lo<<16): hi = RNE bf16 via v_cvt_pk, lo = trunc(h - hi)
__device__ __forceinline__ unsigned hpack(float h) {
    unsigned rp;
    asm("v_cvt_pk_bf16_f32 %0, %1, %1" : "=v"(rp) : "v"(h));
    float lo = h - __uint_as_float(rp << 16);
    return __builtin_amdgcn_perm(__float_as_uint(lo), rp, 0x07060100u);
}

__device__ __forceinline__ float sigm(float x) {
    return __builtin_amdgcn_rcpf(1.0f + __builtin_amdgcn_exp2f(x * -1.4426950408889634f));
}
__device__ __forceinline__ float ftanh(float x) {
    return 1.0f - 2.0f * __builtin_amdgcn_rcpf(1.0f + __builtin_amdgcn_exp2f(x * 2.8853900817779268f));
}

// z = (i,f,g,o) for one unit (lane-local); updates c, returns packed h (hi,lo)
__device__ __forceinline__ unsigned act_unit(const f32x4 z, float& c) {
    float gi = sigm(z[0]), gf = sigm(z[1]), gg = ftanh(z[2]), go = sigm(z[3]);
    c = gf * c + gi * gg;
    return hpack(go * ftanh(c));
}

__device__ __forceinline__ unsigned bperm(int idx, unsigned v) {
    return (unsigned)__builtin_amdgcn_ds_bpermute(idx, (int)v);
}
__device__ __forceinline__ bf16x8 bfrag(unsigned v0, unsigned v1) {
    uint4 u{v0, v0, v1, v1};
    return __builtin_bit_cast(bf16x8, u);
}
__device__ __forceinline__ f32x4 MF(bf16x8 a, bf16x8 b, f32x4 c) {
    return __builtin_amdgcn_mfma_f32_16x16x32_bf16(a, b, c, 0, 0, 0);
}

// ---------- pre-kernel: build A-fragments into ws (15 frags x 64 lanes x 16B) ----------
__global__ void build_afrags(const float* Wk1, const float* Wr1, const float* b1,
                             const float* Wk2, const float* Wr2, const float* b2,
                             const float* Wk3, const float* Wr3, const float* b3,
                             const float* Wd,  const float* bd, unsigned* ws) {
    const int lane = threadIdx.x;  // 64 threads
    const int m = lane & 15;
    const int qh = lane >> 4;

    // ---- L1: ids 0..5 (tau*2+kap), U=10 ----
    for (int tau = 0; tau < 3; ++tau)
    for (int kap = 0; kap < 2; ++kap) {
        unsigned short h8[8];
        for (int j = 0; j < 8; ++j) {
            const int k = kap * 32 + qh * 8 + j;
            const int i = k >> 2, cls = k & 3;
            const int u = tau * 4 + (m >> 2), col = (m & 3) * NU1 + u;
            unsigned short v = 0;
            if (u < NU1) {
                if (i < 15) {
                    float W;
                    if (i < 8)       W = Wr1[((i >> 1) + 4 * (i & 1)) * 40 + col];
                    else if (i < 10) W = Wr1[i * 40 + col];
                    else             W = Wk1[(i - 10) * 40 + col];
                    unsigned short hi = bf16_hi_rne(W);
                    v = (cls < 2) ? hi : bf16_trunc(W - bf16_to_f(hi));
                } else if (i == 15) {
                    float bv = b1[col];
                    unsigned short hi = bf16_hi_rne(bv);
                    v = (cls == 0) ? hi : ((cls == 1) ? bf16_trunc(bv - bf16_to_f(hi)) : (unsigned short)0);
                }
            }
            h8[j] = v;
        }
        const int id = tau * 2 + kap;
        for (int d = 0; d < 4; ++d)
            ws[id * 256 + lane * 4 + d] = (unsigned)h8[2 * d] | ((unsigned)h8[2 * d + 1] << 16);
    }
    // ---- L2: ids 6..11 (6+tau*3+kap), U=7 ----
    for (int tau = 0; tau < 2; ++tau)
    for (int kap = 0; kap < 3; ++kap) {
        unsigned short h8[8];
        for (int j = 0; j < 8; ++j) {
            const int k = kap * 32 + qh * 8 + j;
            const int i = k >> 2, cls = k & 3;
            const int u = tau * 4 + (m >> 2), col = (m & 3) * NU2 + u;
            unsigned short v = 0;
            if (u < NU2) {
                if (i < 17) {
                    float W;
                    if (i < 8)        W = Wk2[((i >> 1) + 4 * (i & 1)) * 28 + col];
                    else if (i < 10)  W = Wk2[i * 28 + col];
                    else if (i < 16)  W = Wr2[(((i - 10) >> 1) + 4 * ((i - 10) & 1)) * 28 + col];
                    else              W = Wr2[3 * 28 + col];
                    unsigned short hi = bf16_hi_rne(W);
                    v = (cls < 2) ? hi : bf16_trunc(W - bf16_to_f(hi));
                } else if (i == 17) {
                    float bv = b2[col];
                    unsigned short hi = bf16_hi_rne(bv);
                    v = (cls == 0) ? hi : ((cls == 1) ? bf16_trunc(bv - bf16_to_f(hi)) : (unsigned short)0);
                }
            }
            h8[j] = v;
        }
        const int id = 6 + tau * 3 + kap;
        for (int d = 0; d < 4; ++d)
            ws[id * 256 + lane * 4 + d] = (unsigned)h8[2 * d] | ((unsigned)h8[2 * d + 1] << 16);
    }
    // ---- L3: ids 12,13, U=4 (single M-tile) ----
    for (int kap = 0; kap < 2; ++kap) {
        unsigned short h8[8];
        for (int j = 0; j < 8; ++j) {
            const int k = kap * 32 + qh * 8 + j;
            const int i = k >> 2, cls = k & 3;
            const int u = m >> 2, col = (m & 3) * NU3 + u;
            unsigned short v = 0;
            if (i < 11) {
                float W;
                if (i < 6)       W = Wk3[((i >> 1) + 4 * (i & 1)) * 16 + col];
                else if (i == 6) W = Wk3[3 * 16 + col];
                else             W = Wr3[(i - 7) * 16 + col];
                unsigned short hi = bf16_hi_rne(W);
                v = (cls < 2) ? hi : bf16_trunc(W - bf16_to_f(hi));
            } else if (i == 11) {
                float bv = b3[col];
                unsigned short hi = bf16_hi_rne(bv);
                v = (cls == 0) ? hi : ((cls == 1) ? bf16_trunc(bv - bf16_to_f(hi)) : (unsigned short)0);
            }
            h8[j] = v;
        }
        const int id = 12 + kap;
        for (int d = 0; d < 4; ++d)
            ws[id * 256 + lane * 4 + d] = (unsigned)h8[2 * d] | ((unsigned)h8[2 * d + 1] << 16);
    }
    // ---- D: id 14, rows REPLICATED: row m -> output (m&3), all row-quads ----
    {
        unsigned short h8[8];
        for (int j = 0; j < 8; ++j) {
            const int k = qh * 8 + j;
            const int i = k >> 2, cls = k & 3;
            unsigned short v = 0;
            if (i < 4) {
                float W = Wd[i * NOUT + (m & 3)];
                unsigned short hi = bf16_hi_rne(W);
                v = (cls < 2) ? hi : bf16_trunc(W - bf16_to_f(hi));
            } else if (i == 4) {
                float bv = bd[m & 3];
                unsigned short hi = bf16_hi_rne(bv);
                v = (cls == 0) ? hi : ((cls == 1) ? bf16_trunc(bv - bf16_to_f(hi)) : (unsigned short)0);
            }
            h8[j] = v;
        }
        for (int d = 0; d < 4; ++d)
            ws[14 * 256 + lane * 4 + d] = (unsigned)h8[2 * d] | ((unsigned)h8[2 * d + 1] << 16);
    }
}

// ---------- main kernel ----------
struct Ctx {
    bf16x8 af[15];
    int i_h19, i_sh, i_r1, i_r2;
    int q;
};

struct Chain {
    const float* xr;
    float* ob;
    unsigned p1a, p1b, p1c, t9, p2a, p2b, p3, rot, rot2;
    unsigned s2a, s2b, xP0, xP1;
    float c10, c11, c12, c20, c21, c30;
    float xa, xc;
    float d0, d1, d2, d3;
    f32x4 z0, z1, z2, y0, y1, w0;
};

__device__ __forceinline__ void ph_init(Chain& S, const float* x, float* out,
                                        int grp, int n, int q) {
    S.xr = x + (size_t)grp * 16 * (SEQ * FEAT) + n * (SEQ * FEAT);
    S.ob = out + (size_t)grp * 16 * (SEQ * NOUT) + n * (SEQ * NOUT);
    S.p1a = S.p1b = S.p1c = S.t9 = S.p2a = S.p2b = S.p3 = S.rot = S.rot2 = 0;
    S.c10 = S.c11 = S.c12 = S.c20 = S.c21 = S.c30 = 0.f;
    S.xa = S.xc = 0.f;
    S.d0 = S.d1 = S.d2 = S.d3 = 0.f;
    if (q != 0) {
        const float* p = S.xr + 2 * (q - 1);
        S.xa = p[0];
        if (q != 3) S.xc = p[1];
    }
}

__device__ __forceinline__ void ph_pre(Chain& S, int t, int q) {
    S.xP0 = hpack(S.xa);
    S.xP1 = hpack(S.xc);
    const int tn = (t + 1 < SEQ) ? t + 1 : 0;
    if (q != 0) {
        const float* p = S.xr + tn * FEAT + 2 * (q - 1);
        S.xa = p[0];
        if (q != 3) S.xc = p[1];
    }
}

__device__ __forceinline__ void ph_L1(Chain& S, const Ctx& C) {
    const f32x4 zro = {0.f, 0.f, 0.f, 0.f};
    bf16x8 bF0 = bfrag(S.p1a, S.p1b);                       // (h1_q, h1_{4+q})^{t-1}
    unsigned F1v0 = (C.q == 0) ? S.p1c : S.xP0;             // h1_8 | x_{2q-2}
    unsigned F1v1 = (C.q == 0) ? S.t9 : ((C.q == 3) ? ONE_P : S.xP1);
    bf16x8 bF1 = bfrag(F1v0, F1v1);
    S.z0 = MF(C.af[0], bF0, zro); S.z0 = MF(C.af[1], bF1, S.z0);
    S.z1 = MF(C.af[2], bF0, zro); S.z1 = MF(C.af[3], bF1, S.z1);
    S.z2 = MF(C.af[4], bF0, zro); S.z2 = MF(C.af[5], bF1, S.z2);
    S.s2a = bperm(C.i_sh, S.p2a);                           // shift h2^{t-1}
    S.s2b = bperm(C.i_sh, S.p2b);
}

__device__ __forceinline__ void ph_act1(Chain& S, const Ctx& C) {
    S.p1a = act_unit(S.z0, S.c10);                          // h1_q^t
    S.p1b = act_unit(S.z1, S.c11);                          // h1_{4+q}^t
    S.p1c = act_unit(S.z2, S.c12);                          // h1_{8+q}^t (q<2)
    S.t9  = bperm(C.i_h19, S.p1c);                          // h1_9^t
}

__device__ __forceinline__ void ph_L2(Chain& S, const Ctx& C) {
    const f32x4 zro = {0.f, 0.f, 0.f, 0.f};
    bf16x8 bA = bfrag(S.p1a, S.p1b);
    unsigned F2v0 = (C.q == 0) ? S.p1c : S.s2a;             // h1_8 | h2_{q-1}
    unsigned F2v1 = (C.q == 0) ? S.t9  : S.s2b;             // h1_9 | h2_{q+3}
    bf16x8 bF2 = bfrag(F2v0, F2v1);
    bf16x8 bF3 = bfrag(S.s2a, ONE_P);                       // q0: (h2_3, b2)
    S.y0 = MF(C.af[6], bA, zro);
    S.y0 = MF(C.af[7], bF2, S.y0);
    S.y0 = MF(C.af[8], bF3, S.y0);
    S.y1 = MF(C.af[9], bA, zro);
    S.y1 = MF(C.af[10], bF2, S.y1);
    S.y1 = MF(C.af[11], bF3, S.y1);
}

__device__ __forceinline__ void ph_act2(Chain& S) {
    S.p2a = act_unit(S.y0, S.c20);                          // h2_q^t
    S.p2b = act_unit(S.y1, S.c21);                          // h2_{4+q}^t (q<3)
}

__device__ __forceinline__ void ph_L3(Chain& S, const Ctx& C) {
    const f32x4 zro = {0.f, 0.f, 0.f, 0.f};
    bf16x8 bF4 = bfrag(S.p2a, (C.q == 3) ? S.rot : S.p2b);  // q3: (h2_3, h3_0^{t-1})
    unsigned F5v0 = (C.q == 0) ? S.rot  : S.rot2;           // h3_1 | h3_3
    unsigned F5v1 = (C.q == 0) ? S.rot2 : ONE_P;            // h3_2 | b3
    bf16x8 bF5 = bfrag(F5v0, F5v1);
    S.w0 = MF(C.af[12], bF4, zro);
    S.w0 = MF(C.af[13], bF5, S.w0);
}

__device__ __forceinline__ void ph_act3(Chain& S, const Ctx& C) {
    S.p3 = act_unit(S.w0, S.c30);                           // h3_q^t
    S.rot  = bperm(C.i_r1, S.p3);                           // h3_{q+1}^t
    S.rot2 = bperm(C.i_r2, S.p3);                           // h3_{q+2}^t
}

__device__ __forceinline__ void ph_D(Chain& S, const Ctx& C, int t) {
    const f32x4 zro = {0.f, 0.f, 0.f, 0.f};
    unsigned F6v0 = (C.q == 0) ? S.p3 : ((C.q == 1) ? S.rot : ONE_P);
    unsigned F6v1 = (C.q == 0) ? S.rot : S.rot2;
    f32x4 o0 = MF(C.af[14], bfrag(F6v0, F6v1), zro);        // all lanes: outputs 0..3
    // keep output index q for this lane
    float v01 = (C.q & 1) ? o0[1] : o0[0];
    float v23 = (C.q & 1) ? o0[3] : o0[2];
    float v = (C.q & 2) ? v23 : v01;
    const int r = t & 3;                                    // uniform
    S.d0 = (r == 0) ? v : S.d0;
    S.d1 = (r == 1) ? v : S.d1;
    S.d2 = (r == 2) ? v : S.d2;
    S.d3 = (r == 3) ? v : S.d3;
}

__device__ __forceinline__ void ph_flush(Chain& S, int t, int q) {
    float* p = S.ob + (t - 3) * NOUT + q;
    p[0 * NOUT] = sigm(S.d0);
    p[1 * NOUT] = sigm(S.d1);
    p[2 * NOUT] = sigm(S.d2);
    p[3 * NOUT] = sigm(S.d3);
}

template <bool DUAL>
__device__ __forceinline__ void run_groups(const Ctx& C, const float* x, float* out,
                                           int g0, int g1, int n, int q) {
    Chain S0, S1;
    ph_init(S0, x, out, g0, n, q);
    if constexpr (DUAL) ph_init(S1, x, out, g1, n, q);
#pragma unroll 1
    for (int t = 0; t < SEQ; ++t) {
        ph_pre(S0, t, q);   if constexpr (DUAL) ph_pre(S1, t, q);
        ph_L1(S0, C);       if constexpr (DUAL) ph_L1(S1, C);
        ph_act1(S0, C);     if constexpr (DUAL) ph_act1(S1, C);
        ph_L2(S0, C);       if constexpr (DUAL) ph_L2(S1, C);
        ph_act2(S0);        if constexpr (DUAL) ph_act2(S1);
        ph_L3(S0, C);       if constexpr (DUAL) ph_L3(S1, C);
        ph_act3(S0, C);     if constexpr (DUAL) ph_act3(S1, C);
        ph_D(S0, C, t);     if constexpr (DUAL) ph_D(S1, C, t);
        if ((t & 3) == 3) {
            ph_flush(S0, t, q);
            if constexpr (DUAL) ph_flush(S1, t, q);
        }
    }
}

__global__ __launch_bounds__(256, 3) void lstm3_mfma(
    const float* __restrict__ x, const unsigned* __restrict__ wsA,
    float* __restrict__ out, int B) {
    const int tid = threadIdx.x;
    const int lane = tid & 63;
    const int n = lane & 15;
    const int q = lane >> 4;

    Ctx C;
#pragma unroll
    for (int i = 0; i < 15; ++i) {
        uint4 v = ((const uint4*)wsA)[i * 64 + lane];
        C.af[i] = __builtin_bit_cast(bf16x8, v);
    }
    C.i_h19 = (n + 16) << 2;
    C.i_sh  = (n + 16 * ((q + 3) & 3)) << 2;
    C.i_r1  = (n + 16 * ((q + 1) & 3)) << 2;
    C.i_r2  = (n + 16 * ((q + 2) & 3)) << 2;
    C.q = q;

    const int ngrp = B >> 4;
    const int gw = (blockIdx.x * blockDim.x + tid) >> 6;
    const int nw = (gridDim.x * blockDim.x) >> 6;

    for (int g0 = 2 * gw; g0 < ngrp; g0 += 2 * nw) {
        const int g1 = g0 + 1;
        if (g1 < ngrp)
            run_groups<true>(C, x, out, g0, g1, n, q);
        else
            run_groups<false>(C, x, out, g0, g0, n, q);
    }
}

extern "C" void kernel_launch(void* const* d_in, const int* in_sizes, int n_in,
                              void* d_out, int out_size, void* d_ws, size_t ws_size,
                              hipStream_t stream) {
    const float* x   = (const float*)d_in[0];
    const float* Wk1 = (const float*)d_in[1];
    const float* Wr1 = (const float*)d_in[2];
    const float* b1  = (const float*)d_in[3];
    const float* Wk2 = (const float*)d_in[4];
    const float* Wr2 = (const float*)d_in[5];
    const float* b2  = (const float*)d_in[6];
    const float* Wk3 = (const float*)d_in[7];
    const float* Wr3 = (const float*)d_in[8];
    const float* b3  = (const float*)d_in[9];
    const float* Wd  = (const float*)d_in[10];
    const float* bd  = (const float*)d_in[11];
    float* out = (float*)d_out;
    unsigned* ws = (unsigned*)d_ws;

    const int B = in_sizes[0] / (SEQ * FEAT);

    build_afrags<<<1, 64, 0, stream>>>(Wk1, Wr1, b1, Wk2, Wr2, b2,
                                       Wk3, Wr3, b3, Wd, bd, ws);
    lstm3_mfma<<<2048, 256, 0, stream>>>(x, ws, out, B);
}